// Round 1
// baseline (259.574 us; speedup 1.0000x reference)
//
#include <hip/hip_runtime.h>
#include <stddef.h>

typedef unsigned short u16;
typedef float f32x4 __attribute__((ext_vector_type(4)));
typedef __bf16 bf16x8 __attribute__((ext_vector_type(8)));

#define NNODES 6144
#define NUMS   3072
#define DIM    256
#define PPERS  4
#define KG     1024   /* P*DIM */
#define NHID   256
#define OFEAT  128

__device__ __forceinline__ u16 f2b(float f) {
  unsigned u = __float_as_uint(f);
  unsigned r = u + 0x7fffu + ((u >> 16) & 1u);   // RNE f32->bf16 (finite inputs)
  return (u16)(r >> 16);
}
__device__ __forceinline__ float b2f(u16 b) {
  return __uint_as_float(((unsigned)b) << 16);
}

__device__ __forceinline__ void gload16(const void* g, void* l) {
  __builtin_amdgcn_global_load_lds((__attribute__((address_space(1))) void*)g,
                                   (__attribute__((address_space(3))) void*)l,
                                   16, 0, 0);
}

// ---------------------------------------------------------------------------
// Build G[n, p*256+d] = 0.5 * (emb[n,d]*glw[p,d]) / max(||emb[n,:]*glw[p,:]||, eps)
// and EMB bf16 copy. One block per node row, 256 threads (d index).
// ---------------------------------------------------------------------------
__global__ void build_g(const float* __restrict__ stru, const float* __restrict__ mm,
                        const float* __restrict__ glw, u16* __restrict__ G,
                        u16* __restrict__ EMB) {
  const int n = blockIdx.x;
  const int d = threadIdx.x;
  const float* src = (n < NUMS) ? (stru + (size_t)n * DIM) : (mm + (size_t)(n - NUMS) * DIM);
  float e = src[d];
  EMB[(size_t)n * DIM + d] = f2b(e);
  __shared__ float red[16];
  float y[PPERS];
#pragma unroll
  for (int p = 0; p < PPERS; ++p) {
    y[p] = e * glw[p * DIM + d];
    float s = y[p] * y[p];
#pragma unroll
    for (int o = 32; o; o >>= 1) s += __shfl_xor(s, o);
    if ((d & 63) == 0) red[p * 4 + (d >> 6)] = s;
  }
  __syncthreads();
#pragma unroll
  for (int p = 0; p < PPERS; ++p) {
    float tot = red[p * 4 + 0] + red[p * 4 + 1] + red[p * 4 + 2] + red[p * 4 + 3];
    float inv = 0.5f / fmaxf(sqrtf(tot), 1e-12f);
    G[(size_t)n * KG + p * DIM + d] = f2b(y[p] * inv);
  }
}

// Transpose + bf16-ify the GCN weights: W0T[j][d] = w0[d][j], W1T[j][d] = w1[d][j]
__global__ void prep_w(const float* __restrict__ w0, const float* __restrict__ w1,
                       u16* __restrict__ W0T, u16* __restrict__ W1T) {
  int t = blockIdx.x * 256 + threadIdx.x;   // grid covers 65536
  {
    int j = t >> 8, d = t & 255;            // t < 256*256
    W0T[t] = f2b(w0[d * NHID + j]);
  }
  if (t < OFEAT * 256) {
    int j = t >> 8, d = t & 255;
    W1T[t] = f2b(w1[d * OFEAT + j]);
  }
}

// ---------------------------------------------------------------------------
// NT bf16 MFMA GEMM: C[m,n] = sum_k A[m,k]*B[n,k]
// 128x128 tile, 4 waves (2x2), each wave 4x4 frags of 16x16x32.
// MODE 0: relu -> bf16 store   (raw_adj)
// MODE 1: plain  -> bf16 store (X0T, HW1T)
// MODE 2: f32 atomicAdd        (split-K hops; C must be zeroed beforehand)
// grid = (N/128, M/128, splits); kPerSplit multiple of 64.
// ---------------------------------------------------------------------------
template <int MODE>
__global__ __launch_bounds__(256, 2)
void gemm_nt(const u16* __restrict__ A, const u16* __restrict__ B, void* __restrict__ Cv,
             int N, int ldA, int ldB, int kPerSplit) {
  __shared__ __align__(16) u16 As[128 * 64];
  __shared__ __align__(16) u16 Bs[128 * 64];
  const int tid = threadIdx.x;
  const int lane = tid & 63;
  const int wv = tid >> 6;
  const int m0 = blockIdx.y * 128;
  const int n0 = blockIdx.x * 128;
  const int kBeg = blockIdx.z * kPerSplit;
  const int kEnd = kBeg + kPerSplit;
  const int wr = wv >> 1, wc = wv & 1;
  const int lrow = lane & 15, kg = lane >> 4;

  f32x4 acc[4][4];
  const f32x4 zero = {0.f, 0.f, 0.f, 0.f};
#pragma unroll
  for (int i = 0; i < 4; ++i)
#pragma unroll
    for (int j = 0; j < 4; ++j) acc[i][j] = zero;

  for (int kt = kBeg; kt < kEnd; kt += 64) {
    __syncthreads();
    // stage A-tile [128][64] and B-tile [128][64] linearly into LDS
#pragma unroll
    for (int i = 0; i < 4; ++i) {
      int pos = i * 256 + wv * 64 + lane;      // 0..1023
      int r = pos >> 3;                        // tile row
      int c = (pos & 7) * 8;                   // bf16 col start (16B chunk)
      int dstOff = (i * 256 + wv * 64) * 16;   // wave-uniform LDS byte base
      gload16(A + (size_t)(m0 + r) * ldA + kt + c, (char*)As + dstOff);
      gload16(B + (size_t)(n0 + r) * ldB + kt + c, (char*)Bs + dstOff);
    }
    __syncthreads();
#pragma unroll
    for (int kk = 0; kk < 2; ++kk) {
      bf16x8 a[4], b[4];
#pragma unroll
      for (int mi = 0; mi < 4; ++mi)
        a[mi] = *(const bf16x8*)&As[(wr * 64 + mi * 16 + lrow) * 64 + kk * 32 + kg * 8];
#pragma unroll
      for (int ni = 0; ni < 4; ++ni)
        b[ni] = *(const bf16x8*)&Bs[(wc * 64 + ni * 16 + lrow) * 64 + kk * 32 + kg * 8];
#pragma unroll
      for (int mi = 0; mi < 4; ++mi)
#pragma unroll
        for (int ni = 0; ni < 4; ++ni)
          acc[mi][ni] = __builtin_amdgcn_mfma_f32_16x16x32_bf16(a[mi], b[ni], acc[mi][ni], 0, 0, 0);
    }
  }

  u16* Cb = (u16*)Cv;
  float* Cf = (float*)Cv;
#pragma unroll
  for (int mi = 0; mi < 4; ++mi) {
#pragma unroll
    for (int r = 0; r < 4; ++r) {
      int row = m0 + wr * 64 + mi * 16 + kg * 4 + r;  // C/D: row=(l>>4)*4+r, col=l&15
      size_t base = (size_t)row * N;
#pragma unroll
      for (int ni = 0; ni < 4; ++ni) {
        int col = n0 + wc * 64 + ni * 16 + lrow;
        float v = acc[mi][ni][r];
        if (MODE == 0) {
          Cb[base + col] = f2b(fmaxf(v, 0.0f));
        } else if (MODE == 1) {
          Cb[base + col] = f2b(v);
        } else {
          atomicAdd(&Cf[base + col], v);
        }
      }
    }
  }
}

// Row sums of bf16 raw_adj -> invrow[n] = 1/max(sum, eps)
__global__ void rowsum_kernel(const u16* __restrict__ adj, float* __restrict__ invrow) {
  const int n = blockIdx.x;
  const u16* row = adj + (size_t)n * NNODES;
  float s = 0.f;
  for (int c = threadIdx.x * 8; c < NNODES; c += 256 * 8) {
    bf16x8 v = *(const bf16x8*)(row + c);   // 8 bf16 bits
    const u16* pv = (const u16*)&v;
#pragma unroll
    for (int j = 0; j < 8; ++j) s += b2f(pv[j]);
  }
#pragma unroll
  for (int o = 32; o; o >>= 1) s += __shfl_xor(s, o);
  __shared__ float red[4];
  if ((threadIdx.x & 63) == 0) red[threadIdx.x >> 6] = s;
  __syncthreads();
  if (threadIdx.x == 0) {
    float t = red[0] + red[1] + red[2] + red[3];
    invrow[n] = 1.0f / fmaxf(t, 1e-12f);
  }
}

// H[n][j] = bf16(relu(OUT1[n][j]*invrow[n] + b0[j]))
__global__ void h_epi(const float* __restrict__ O1, const float* __restrict__ invrow,
                      const float* __restrict__ b0, u16* __restrict__ H) {
  int n = blockIdx.x, j = threadIdx.x;
  float v = O1[(size_t)n * NHID + j] * invrow[n] + b0[j];
  H[(size_t)n * NHID + j] = f2b(fmaxf(v, 0.0f));
}

// out[n][j] = log_softmax_j( OUT2[n][j]*invrow[n] + b1[j] ); 128 threads = 2 waves
__global__ void final_ls(const float* __restrict__ O2, const float* __restrict__ invrow,
                         const float* __restrict__ b1, float* __restrict__ out) {
  int n = blockIdx.x, j = threadIdx.x;
  float x = O2[(size_t)n * OFEAT + j] * invrow[n] + b1[j];
  float m = x;
#pragma unroll
  for (int o = 32; o; o >>= 1) m = fmaxf(m, __shfl_xor(m, o));
  __shared__ float rm[2], rs[2];
  if ((j & 63) == 0) rm[j >> 6] = m;
  __syncthreads();
  m = fmaxf(rm[0], rm[1]);
  float e = expf(x - m);
  float s = e;
#pragma unroll
  for (int o = 32; o; o >>= 1) s += __shfl_xor(s, o);
  if ((j & 63) == 0) rs[j >> 6] = s;
  __syncthreads();
  s = rs[0] + rs[1];
  out[(size_t)n * OFEAT + j] = x - m - logf(s);
}

extern "C" void kernel_launch(void* const* d_in, const int* in_sizes, int n_in,
                              void* d_out, int out_size, void* d_ws, size_t ws_size,
                              hipStream_t stream) {
  const float* stru = (const float*)d_in[0];
  const float* mm   = (const float*)d_in[1];
  const float* glw  = (const float*)d_in[2];
  const float* w0   = (const float*)d_in[3];
  const float* b0   = (const float*)d_in[4];
  const float* w1   = (const float*)d_in[5];
  const float* b1   = (const float*)d_in[6];
  float* out = (float*)d_out;

  char* ws = (char*)d_ws;
  size_t off = 0;
  auto carve = [&](size_t bytes) -> void* {
    void* p = ws + off;
    off += (bytes + 255) & ~(size_t)255;
    return p;
  };
  u16*   G     = (u16*)carve((size_t)NNODES * KG * 2);        // 12.6 MB
  u16*   EMB   = (u16*)carve((size_t)NNODES * DIM * 2);       // 3.1 MB
  u16*   W0T   = (u16*)carve((size_t)NHID * DIM * 2);         // 128 KB
  u16*   W1T   = (u16*)carve((size_t)OFEAT * DIM * 2);        // 64 KB
  u16*   ADJ   = (u16*)carve((size_t)NNODES * NNODES * 2);    // 75.5 MB
  float* INV   = (float*)carve((size_t)NNODES * 4);
  u16*   X0T   = (u16*)carve((size_t)NHID * NNODES * 2);      // 3.1 MB
  u16*   H     = (u16*)carve((size_t)NNODES * NHID * 2);      // 3.1 MB
  u16*   HW1T  = (u16*)carve((size_t)OFEAT * NNODES * 2);     // 1.6 MB
  float* OUT1  = (float*)carve((size_t)NNODES * NHID * 4);    // 6.3 MB
  float* OUT2  = (float*)carve((size_t)NNODES * OFEAT * 4);   // 3.1 MB

  // zero split-K accumulators (atomicAdd targets) every call
  hipMemsetAsync(OUT1, 0, (size_t)NNODES * NHID * 4, stream);
  hipMemsetAsync(OUT2, 0, (size_t)NNODES * OFEAT * 4, stream);

  build_g<<<NNODES, 256, 0, stream>>>(stru, mm, glw, G, EMB);
  prep_w<<<256, 256, 0, stream>>>(w0, w1, W0T, W1T);

  // S = G * G^T, relu -> bf16 raw_adj. M=N=6144, K=1024
  gemm_nt<0><<<dim3(48, 48, 1), 256, 0, stream>>>(G, G, ADJ, NNODES, KG, KG, KG);

  rowsum_kernel<<<NNODES, 256, 0, stream>>>(ADJ, INV);

  // X0T[j][node] = sum_d W0T[j][d]*EMB[node][d]. M=256, N=6144, K=256
  gemm_nt<1><<<dim3(48, 2, 1), 256, 0, stream>>>(W0T, EMB, X0T, NNODES, DIM, DIM, DIM);

  // OUT1 = raw_adj @ X0 (split-K 8). M=6144, N=256, K=6144
  gemm_nt<2><<<dim3(2, 48, 8), 256, 0, stream>>>(ADJ, X0T, OUT1, NHID, NNODES, NNODES, 768);

  h_epi<<<NNODES, NHID, 0, stream>>>(OUT1, INV, b0, H);

  // HW1T[j][node] = sum_d W1T[j][d]*H[node][d]. M=128, N=6144, K=256
  gemm_nt<1><<<dim3(48, 1, 1), 256, 0, stream>>>(W1T, H, HW1T, NNODES, DIM, DIM, DIM);

  // OUT2 = raw_adj @ HW1 (split-K 16). M=6144, N=128, K=6144
  gemm_nt<2><<<dim3(1, 48, 16), 256, 0, stream>>>(ADJ, HW1T, OUT2, OFEAT, NNODES, NNODES, 384);

  final_ls<<<NNODES, OFEAT, 0, stream>>>(OUT2, INV, b1, out);

  (void)in_sizes; (void)n_in; (void)out_size; (void)ws_size;
}

// Round 2
// 236.285 us; speedup vs baseline: 1.0986x; 1.0986x over previous
//
#include <hip/hip_runtime.h>
#include <stddef.h>

typedef unsigned short u16;
typedef float f32x4 __attribute__((ext_vector_type(4)));
typedef __bf16 bf16x8 __attribute__((ext_vector_type(8)));
typedef unsigned int u32;
typedef u32 u32x2 __attribute__((ext_vector_type(2)));

#define NNODES 6144
#define NUMS   3072
#define DIM    256
#define PPERS  4
#define KG     1024   /* P*DIM */
#define NHID   256
#define OFEAT  128

__device__ __forceinline__ u16 f2b(float f) {
  unsigned u = __float_as_uint(f);
  unsigned r = u + 0x7fffu + ((u >> 16) & 1u);   // RNE f32->bf16 (finite inputs)
  return (u16)(r >> 16);
}

__device__ __forceinline__ void gload16(const void* g, void* l) {
  __builtin_amdgcn_global_load_lds((__attribute__((address_space(1))) void*)g,
                                   (__attribute__((address_space(3))) void*)l,
                                   16, 0, 0);
}

// ---------------------------------------------------------------------------
// Build G[n, p*256+d] = 0.5 * (emb[n,d]*glw[p,d]) / max(||emb[n,:]*glw[p,:]||, eps)
// and EMB bf16 copy. One block per node row, 256 threads (d index).
// ---------------------------------------------------------------------------
__global__ void build_g(const float* __restrict__ stru, const float* __restrict__ mm,
                        const float* __restrict__ glw, u16* __restrict__ G,
                        u16* __restrict__ EMB) {
  const int n = blockIdx.x;
  const int d = threadIdx.x;
  const float* src = (n < NUMS) ? (stru + (size_t)n * DIM) : (mm + (size_t)(n - NUMS) * DIM);
  float e = src[d];
  EMB[(size_t)n * DIM + d] = f2b(e);
  __shared__ float red[16];
  float y[PPERS];
#pragma unroll
  for (int p = 0; p < PPERS; ++p) {
    y[p] = e * glw[p * DIM + d];
    float s = y[p] * y[p];
#pragma unroll
    for (int o = 32; o; o >>= 1) s += __shfl_xor(s, o);
    if ((d & 63) == 0) red[p * 4 + (d >> 6)] = s;
  }
  __syncthreads();
#pragma unroll
  for (int p = 0; p < PPERS; ++p) {
    float tot = red[p * 4 + 0] + red[p * 4 + 1] + red[p * 4 + 2] + red[p * 4 + 3];
    float inv = 0.5f / fmaxf(sqrtf(tot), 1e-12f);
    G[(size_t)n * KG + p * DIM + d] = f2b(y[p] * inv);
  }
}

// Transpose + bf16-ify the GCN weights: W0T[j][d] = w0[d][j], W1T[j][d] = w1[d][j]
__global__ void prep_w(const float* __restrict__ w0, const float* __restrict__ w1,
                       u16* __restrict__ W0T, u16* __restrict__ W1T) {
  int t = blockIdx.x * 256 + threadIdx.x;   // grid covers 65536
  {
    int j = t >> 8, d = t & 255;            // t < 256*256
    W0T[t] = f2b(w0[d * NHID + j]);
  }
  if (t < OFEAT * 256) {
    int j = t >> 8, d = t & 255;
    W1T[t] = f2b(w1[d * OFEAT + j]);
  }
}

// ---------------------------------------------------------------------------
// Symmetric Gram GEMM: S = G*G^T (M=N=6144, K=1024), relu epilogue,
// lower-triangle tile grid (1176 blocks), dual write (tile + LDS-transposed),
// fused row-sum atomics into RSUM (f32, must be zeroed).
// ---------------------------------------------------------------------------
__global__ __launch_bounds__(256, 2)
void gemm_sym(const u16* __restrict__ G, u16* __restrict__ ADJ, float* __restrict__ RSUM) {
  // triangle decode: t -> (rT, cT), cT <= rT, rT in [0,48)
  int t = blockIdx.x;
  int rT = (int)((sqrtf(8.0f * (float)t + 1.0f) - 1.0f) * 0.5f);
  while ((rT + 1) * (rT + 2) / 2 <= t) ++rT;
  while (rT * (rT + 1) / 2 > t) --rT;
  const int cT = t - rT * (rT + 1) / 2;
  const int m0 = rT * 128;       // rows of this tile
  const int n0 = cT * 128;       // cols of this tile (n0 <= m0)
  const bool diag = (rT == cT);

  __shared__ __align__(16) u16 SMEM[128 * 136];   // As|Bs during K-loop; T in epilogue
  u16* As = SMEM;               // [128][64]
  u16* Bs = SMEM + 128 * 64;    // [128][64]

  const int tid = threadIdx.x;
  const int lane = tid & 63;
  const int wv = tid >> 6;
  const int wr = wv >> 1, wc = wv & 1;
  const int lrow = lane & 15, kg = lane >> 4;

  f32x4 acc[4][4];
  const f32x4 zero = {0.f, 0.f, 0.f, 0.f};
#pragma unroll
  for (int i = 0; i < 4; ++i)
#pragma unroll
    for (int j = 0; j < 4; ++j) acc[i][j] = zero;

  for (int kt = 0; kt < KG; kt += 64) {
    __syncthreads();
#pragma unroll
    for (int i = 0; i < 4; ++i) {
      int pos = i * 256 + wv * 64 + lane;      // 0..1023
      int r = pos >> 3;
      int c = (pos & 7) * 8;
      int dstOff = (i * 256 + wv * 64) * 16;   // wave-uniform LDS byte base
      gload16(G + (size_t)(m0 + r) * KG + kt + c, (char*)As + dstOff);
      gload16(G + (size_t)(n0 + r) * KG + kt + c, (char*)Bs + dstOff);
    }
    __syncthreads();
#pragma unroll
    for (int kk = 0; kk < 2; ++kk) {
      bf16x8 a[4], b[4];
#pragma unroll
      for (int mi = 0; mi < 4; ++mi)
        a[mi] = *(const bf16x8*)&As[(wr * 64 + mi * 16 + lrow) * 64 + kk * 32 + kg * 8];
#pragma unroll
      for (int ni = 0; ni < 4; ++ni)
        b[ni] = *(const bf16x8*)&Bs[(wc * 64 + ni * 16 + lrow) * 64 + kk * 32 + kg * 8];
#pragma unroll
      for (int mi = 0; mi < 4; ++mi)
#pragma unroll
        for (int ni = 0; ni < 4; ++ni)
          acc[mi][ni] = __builtin_amdgcn_mfma_f32_16x16x32_bf16(a[mi], b[ni], acc[mi][ni], 0, 0, 0);
    }
  }

  __syncthreads();   // all waves done with As/Bs before T overwrites SMEM

  // relu'd values
  float rv[4][4][4];
#pragma unroll
  for (int mi = 0; mi < 4; ++mi)
#pragma unroll
    for (int ni = 0; ni < 4; ++ni)
#pragma unroll
      for (int r = 0; r < 4; ++r) rv[mi][ni][r] = fmaxf(acc[mi][ni][r], 0.0f);

  // direct store of the (m0,n0) tile + pack transposed into SMEM (off-diag)
#pragma unroll
  for (int mi = 0; mi < 4; ++mi) {
#pragma unroll
    for (int r = 0; r < 4; ++r) {
      int row = m0 + wr * 64 + mi * 16 + kg * 4 + r;   // C/D: row=(l>>4)*4+r, col=l&15
      size_t base = (size_t)row * NNODES;
#pragma unroll
      for (int ni = 0; ni < 4; ++ni) {
        int col = n0 + wc * 64 + ni * 16 + lrow;
        ADJ[base + col] = f2b(rv[mi][ni][r]);
      }
    }
    if (!diag) {
      // T[c][rowLocal]: pack 4 consecutive rows (r=0..3) into one 8B write
#pragma unroll
      for (int ni = 0; ni < 4; ++ni) {
        int cl = wc * 64 + ni * 16 + lrow;          // local col
        int rl0 = wr * 64 + mi * 16 + kg * 4;       // local row base (mult of 4)
        u32x2 pack;
        pack[0] = (u32)f2b(rv[mi][ni][0]) | ((u32)f2b(rv[mi][ni][1]) << 16);
        pack[1] = (u32)f2b(rv[mi][ni][2]) | ((u32)f2b(rv[mi][ni][3]) << 16);
        *(u32x2*)&SMEM[cl * 136 + rl0] = pack;
      }
    }
  }

  // fused row sums (row side): rows m0.., sum over this tile's 128 cols
#pragma unroll
  for (int mi = 0; mi < 4; ++mi) {
#pragma unroll
    for (int r = 0; r < 4; ++r) {
      float s = rv[mi][0][r] + rv[mi][1][r] + rv[mi][2][r] + rv[mi][3][r];
      s += __shfl_xor(s, 1); s += __shfl_xor(s, 2);
      s += __shfl_xor(s, 4); s += __shfl_xor(s, 8);
      if (lrow == 0) atomicAdd(&RSUM[m0 + wr * 64 + mi * 16 + kg * 4 + r], s);
    }
  }

  if (!diag) {
    // col side -> rows n0.. of the symmetric matrix
#pragma unroll
    for (int ni = 0; ni < 4; ++ni) {
      float s = 0.f;
#pragma unroll
      for (int mi = 0; mi < 4; ++mi)
#pragma unroll
        for (int r = 0; r < 4; ++r) s += rv[mi][ni][r];
      s += __shfl_xor(s, 16); s += __shfl_xor(s, 32);
      if (kg == 0) atomicAdd(&RSUM[n0 + wc * 64 + ni * 16 + lrow], s);
    }
    __syncthreads();
    // coalesced store of transposed tile: ADJ[n0+rr][m0 + 0..127]
#pragma unroll
    for (int it = 0; it < 8; ++it) {
      int cid = it * 256 + tid;        // 2048 chunks of 8 bf16
      int rr = cid >> 4;
      int c8 = (cid & 15) * 8;
      bf16x8 v = *(const bf16x8*)&SMEM[rr * 136 + c8];
      *(bf16x8*)&ADJ[(size_t)(n0 + rr) * NNODES + m0 + c8] = v;
    }
  }
}

// ---------------------------------------------------------------------------
// NT bf16 MFMA GEMM: C[m,n] = sum_k A[m,k]*B[n,k]
// MODE 1: plain -> bf16 store (X0T, HW1T)
// MODE 2: f32 atomicAdd       (split-K hops; C must be zeroed beforehand)
// grid = (N/128, M/128, splits); kPerSplit multiple of 64.
// ---------------------------------------------------------------------------
template <int MODE>
__global__ __launch_bounds__(256, 2)
void gemm_nt(const u16* __restrict__ A, const u16* __restrict__ B, void* __restrict__ Cv,
             int N, int ldA, int ldB, int kPerSplit) {
  __shared__ __align__(16) u16 As[128 * 64];
  __shared__ __align__(16) u16 Bs[128 * 64];
  const int tid = threadIdx.x;
  const int lane = tid & 63;
  const int wv = tid >> 6;
  const int m0 = blockIdx.y * 128;
  const int n0 = blockIdx.x * 128;
  const int kBeg = blockIdx.z * kPerSplit;
  const int kEnd = kBeg + kPerSplit;
  const int wr = wv >> 1, wc = wv & 1;
  const int lrow = lane & 15, kg = lane >> 4;

  f32x4 acc[4][4];
  const f32x4 zero = {0.f, 0.f, 0.f, 0.f};
#pragma unroll
  for (int i = 0; i < 4; ++i)
#pragma unroll
    for (int j = 0; j < 4; ++j) acc[i][j] = zero;

  for (int kt = kBeg; kt < kEnd; kt += 64) {
    __syncthreads();
#pragma unroll
    for (int i = 0; i < 4; ++i) {
      int pos = i * 256 + wv * 64 + lane;
      int r = pos >> 3;
      int c = (pos & 7) * 8;
      int dstOff = (i * 256 + wv * 64) * 16;
      gload16(A + (size_t)(m0 + r) * ldA + kt + c, (char*)As + dstOff);
      gload16(B + (size_t)(n0 + r) * ldB + kt + c, (char*)Bs + dstOff);
    }
    __syncthreads();
#pragma unroll
    for (int kk = 0; kk < 2; ++kk) {
      bf16x8 a[4], b[4];
#pragma unroll
      for (int mi = 0; mi < 4; ++mi)
        a[mi] = *(const bf16x8*)&As[(wr * 64 + mi * 16 + lrow) * 64 + kk * 32 + kg * 8];
#pragma unroll
      for (int ni = 0; ni < 4; ++ni)
        b[ni] = *(const bf16x8*)&Bs[(wc * 64 + ni * 16 + lrow) * 64 + kk * 32 + kg * 8];
#pragma unroll
      for (int mi = 0; mi < 4; ++mi)
#pragma unroll
        for (int ni = 0; ni < 4; ++ni)
          acc[mi][ni] = __builtin_amdgcn_mfma_f32_16x16x32_bf16(a[mi], b[ni], acc[mi][ni], 0, 0, 0);
    }
  }

  u16* Cb = (u16*)Cv;
  float* Cf = (float*)Cv;
#pragma unroll
  for (int mi = 0; mi < 4; ++mi) {
#pragma unroll
    for (int r = 0; r < 4; ++r) {
      int row = m0 + wr * 64 + mi * 16 + kg * 4 + r;
      size_t base = (size_t)row * N;
#pragma unroll
      for (int ni = 0; ni < 4; ++ni) {
        int col = n0 + wc * 64 + ni * 16 + lrow;
        float v = acc[mi][ni][r];
        if (MODE == 1) {
          Cb[base + col] = f2b(v);
        } else {
          atomicAdd(&Cf[base + col], v);
        }
      }
    }
  }
}

// H[n][j] = bf16(relu(OUT1[n][j]/rowsum[n] + b0[j]))
__global__ void h_epi(const float* __restrict__ O1, const float* __restrict__ RSUM,
                      const float* __restrict__ b0, u16* __restrict__ H) {
  int n = blockIdx.x, j = threadIdx.x;
  float inv = 1.0f / fmaxf(RSUM[n], 1e-12f);
  float v = O1[(size_t)n * NHID + j] * inv + b0[j];
  H[(size_t)n * NHID + j] = f2b(fmaxf(v, 0.0f));
}

// out[n][j] = log_softmax_j( OUT2[n][j]/rowsum[n] + b1[j] ); 128 threads = 2 waves
__global__ void final_ls(const float* __restrict__ O2, const float* __restrict__ RSUM,
                         const float* __restrict__ b1, float* __restrict__ out) {
  int n = blockIdx.x, j = threadIdx.x;
  float inv = 1.0f / fmaxf(RSUM[n], 1e-12f);
  float x = O2[(size_t)n * OFEAT + j] * inv + b1[j];
  float m = x;
#pragma unroll
  for (int o = 32; o; o >>= 1) m = fmaxf(m, __shfl_xor(m, o));
  __shared__ float rm[2], rs[2];
  if ((j & 63) == 0) rm[j >> 6] = m;
  __syncthreads();
  m = fmaxf(rm[0], rm[1]);
  float e = expf(x - m);
  float s = e;
#pragma unroll
  for (int o = 32; o; o >>= 1) s += __shfl_xor(s, o);
  if ((j & 63) == 0) rs[j >> 6] = s;
  __syncthreads();
  s = rs[0] + rs[1];
  out[(size_t)n * OFEAT + j] = x - m - logf(s);
}

extern "C" void kernel_launch(void* const* d_in, const int* in_sizes, int n_in,
                              void* d_out, int out_size, void* d_ws, size_t ws_size,
                              hipStream_t stream) {
  const float* stru = (const float*)d_in[0];
  const float* mm   = (const float*)d_in[1];
  const float* glw  = (const float*)d_in[2];
  const float* w0   = (const float*)d_in[3];
  const float* b0   = (const float*)d_in[4];
  const float* w1   = (const float*)d_in[5];
  const float* b1   = (const float*)d_in[6];
  float* out = (float*)d_out;

  char* ws = (char*)d_ws;
  size_t off = 0;
  auto carve = [&](size_t bytes) -> void* {
    void* p = ws + off;
    off += (bytes + 255) & ~(size_t)255;
    return p;
  };
  u16*   G     = (u16*)carve((size_t)NNODES * KG * 2);        // 12.6 MB
  u16*   EMB   = (u16*)carve((size_t)NNODES * DIM * 2);       // 3.1 MB
  u16*   W0T   = (u16*)carve((size_t)NHID * DIM * 2);         // 128 KB
  u16*   W1T   = (u16*)carve((size_t)OFEAT * DIM * 2);        // 64 KB
  u16*   ADJ   = (u16*)carve((size_t)NNODES * NNODES * 2);    // 75.5 MB
  float* RSUM  = (float*)carve((size_t)NNODES * 4);
  u16*   X0T   = (u16*)carve((size_t)NHID * NNODES * 2);      // 3.1 MB
  u16*   H     = (u16*)carve((size_t)NNODES * NHID * 2);      // 3.1 MB
  u16*   HW1T  = (u16*)carve((size_t)OFEAT * NNODES * 2);     // 1.6 MB
  float* OUT1  = (float*)carve((size_t)NNODES * NHID * 4);    // 6.3 MB
  float* OUT2  = (float*)carve((size_t)NNODES * OFEAT * 4);   // 3.1 MB

  // zero atomic accumulators every call
  hipMemsetAsync(RSUM, 0, (size_t)NNODES * 4, stream);
  hipMemsetAsync(OUT1, 0, (size_t)NNODES * NHID * 4, stream);
  hipMemsetAsync(OUT2, 0, (size_t)NNODES * OFEAT * 4, stream);

  build_g<<<NNODES, 256, 0, stream>>>(stru, mm, glw, G, EMB);
  prep_w<<<256, 256, 0, stream>>>(w0, w1, W0T, W1T);

  // S = G*G^T, relu -> bf16 raw_adj (dual write) + fused rowsum. Lower-tri grid.
  gemm_sym<<<48 * 49 / 2, 256, 0, stream>>>(G, ADJ, RSUM);

  // X0T[j][node] = sum_d W0T[j][d]*EMB[node][d]. M=256, N=6144, K=256
  gemm_nt<1><<<dim3(48, 2, 1), 256, 0, stream>>>(W0T, EMB, X0T, NNODES, DIM, DIM, DIM);

  // OUT1 = raw_adj @ X0 (split-K 8). M=6144, N=256, K=6144
  gemm_nt<2><<<dim3(2, 48, 8), 256, 0, stream>>>(ADJ, X0T, OUT1, NHID, NNODES, NNODES, 768);

  h_epi<<<NNODES, NHID, 0, stream>>>(OUT1, RSUM, b0, H);

  // HW1T[j][node] = sum_d W1T[j][d]*H[node][d]. M=128, N=6144, K=256
  gemm_nt<1><<<dim3(48, 1, 1), 256, 0, stream>>>(W1T, H, HW1T, NNODES, DIM, DIM, DIM);

  // OUT2 = raw_adj @ HW1 (split-K 16). M=6144, N=128, K=6144
  gemm_nt<2><<<dim3(1, 48, 16), 256, 0, stream>>>(ADJ, HW1T, OUT2, OFEAT, NNODES, NNODES, 384);

  final_ls<<<NNODES, OFEAT, 0, stream>>>(OUT2, RSUM, b1, out);

  (void)in_sizes; (void)n_in; (void)out_size; (void)ws_size;
}